// Round 7
// baseline (105.731 us; speedup 1.0000x reference)
//
#include <hip/hip_runtime.h>
#include <math.h>

#define BATCH_N 884736    // 96*96*96
#define NTOT   1769472    // 2*BATCH_N
#define WPB 4             // waves per k_gemm block
#define THREADS 256
#define GBX 384           // blocks per batch -> 768 total = exactly 3/CU
#define GWAVES 1536       // waves per batch: 13824/1536 = exactly 9 chunks/wave
#define NCHUNK 9
#define KBLK 512          // k_minmax blocks
#define QS 190.0f         // weight quantization scale (max w=2/3 -> 127)

// voxel-major tile: 6 bin-blocks x (64 vox x 16 bins) bytes; padded bin = bin+16
// so real bins 0..63 occupy blocks 1..4 exactly; blocks 0 and 5 absorb edges.
#define BBLK_B 1024
#define TILE_B 6144       // per matrix
#define WAVE_B 12288      // A+B per wave
#define MROW 66           // merge region row stride (floats)

// ws layout (bytes):
//   ghist  at   256 : float[2][4096]   (zeroed by k_minmax; atomic-accumulated by k_gemm)
//   kblk   at 36864 : uint4[512]       (plain-stored by k_minmax)
#define OFF_GHIST 256
#define OFF_KBLK 36864

typedef int v4i __attribute__((ext_vector_type(4)));
typedef int v2i __attribute__((ext_vector_type(2)));

// monotone float->uint key: max over keys == max over floats
__device__ __forceinline__ unsigned fkey(float x){
    unsigned u = __float_as_uint(x);
    return (u & 0x80000000u) ? ~u : (u | 0x80000000u);
}
__device__ __forceinline__ float fdecode(unsigned k){
    return __uint_as_float((k & 0x80000000u) ? (k ^ 0x80000000u) : ~k);
}

// cubic B-spline weights for bins it0-1..it0+2, u = frac(v) in [0,1)
__device__ __forceinline__ void bw4(float u, float w[4]){
    float um = 1.f - u;
    float u2 = u*u, um2 = um*um;
    w[0] = um2*um*(1.f/6.f);
    w[3] = u2*u*(1.f/6.f);
    w[1] = 0.6666666666666667f - u2 + 0.5f*u2*u;
    w[2] = 0.6666666666666667f - um2 + 0.5f*um2*um;
}

// quantize 4 weights, position them into a 16-byte row image (+spill row)
// starting at padded byte col c = i0+15 within bin-blocks g, g+1.
#define PACK(val, mn, sc, G, MV, SV) do { \
    float v_ = ((val) - (mn)) * (sc); \
    int i0_ = (int)v_; \
    float w_[4]; bw4(v_ - (float)i0_, w_); \
    unsigned W_ = (unsigned)__float2int_rn(w_[0]*QS) \
                | ((unsigned)__float2int_rn(w_[1]*QS) << 8) \
                | ((unsigned)__float2int_rn(w_[2]*QS) << 16) \
                | ((unsigned)__float2int_rn(w_[3]*QS) << 24); \
    int c_ = i0_ + 15; \
    G = c_ >> 4; \
    int sh_ = (c_ & 15) << 3; \
    unsigned long long W64_ = W_; \
    unsigned long long lo_ = (sh_ < 64) ? (W64_ << sh_) : 0ull; \
    unsigned long long hi_ = (sh_ < 64) ? (sh_ ? (W64_ >> (64 - sh_)) : 0ull) \
                                        : (W64_ << (sh_ - 64)); \
    unsigned long long sp_ = (sh_ > 96) ? (W64_ >> (128 - sh_)) : 0ull; \
    MV = (v4i){(int)lo_, (int)(lo_>>32), (int)hi_, (int)(hi_>>32)}; \
    SV = (v4i){(int)sp_, (int)(sp_>>32), 0, 0}; \
} while(0)

// per-block min/max -> plain store into kblk[block]; blocks 0..7 also zero ghist
__global__ void __launch_bounds__(256)
k_minmax(const float4* __restrict__ t4, const float4* __restrict__ s4,
         int n4, uint4* __restrict__ kblk, float* __restrict__ ghist){
    __shared__ unsigned red[4][4];   // [wave][key]

    if (blockIdx.x < 8){
        ghist[blockIdx.x*1024 + threadIdx.x] = 0.f;
        ghist[blockIdx.x*1024 + 256 + threadIdx.x] = 0.f;
        ghist[blockIdx.x*1024 + 512 + threadIdx.x] = 0.f;
        ghist[blockIdx.x*1024 + 768 + threadIdx.x] = 0.f;
    }

    unsigned mt=0u, mnt=0u, ms=0u, mns=0u;
    int stride = gridDim.x * blockDim.x;
    for (int i = blockIdx.x*blockDim.x + threadIdx.x; i < n4; i += stride){
        float4 a = t4[i];
        float4 b = s4[i];
        mt  = max(mt,  max(max(fkey(a.x),  fkey(a.y)),  max(fkey(a.z),  fkey(a.w))));
        mnt = max(mnt, max(max(fkey(-a.x), fkey(-a.y)), max(fkey(-a.z), fkey(-a.w))));
        ms  = max(ms,  max(max(fkey(b.x),  fkey(b.y)),  max(fkey(b.z),  fkey(b.w))));
        mns = max(mns, max(max(fkey(-b.x), fkey(-b.y)), max(fkey(-b.z), fkey(-b.w))));
    }
    #pragma unroll
    for (int off = 32; off; off >>= 1){
        mt  = max(mt,  __shfl_down(mt,  off));
        mnt = max(mnt, __shfl_down(mnt, off));
        ms  = max(ms,  __shfl_down(ms,  off));
        mns = max(mns, __shfl_down(mns, off));
    }
    int wid = threadIdx.x >> 6;
    if ((threadIdx.x & 63) == 0){
        red[wid][0] = mt; red[wid][1] = mnt; red[wid][2] = ms; red[wid][3] = mns;
    }
    __syncthreads();
    if (threadIdx.x == 0){
        uint4 q;
        q.x = max(max(red[0][0], red[1][0]), max(red[2][0], red[3][0]));
        q.y = max(max(red[0][1], red[1][1]), max(red[2][1], red[3][1]));
        q.z = max(max(red[0][2], red[1][2]), max(red[2][2], red[3][2]));
        q.w = max(max(red[0][3], red[1][3]), max(red[2][3], red[3][3]));
        kblk[blockIdx.x] = q;
    }
}

// joint histogram as tall-skinny GEMM on int8, voxel-major LDS tiles:
// scatter = 2 aligned bank-uniform ds_write_b128 per matrix; fragments via
// ds_read_b64_tr_b8 hardware transpose (R4-verified geometry). Pack for chunk
// n+1 computed between read-issue and the lgkm fence (hides DS latency).
// 4 waves/block, 768 blocks = exactly 3/CU (12 waves/CU), 9 chunks/wave.
__global__ void __launch_bounds__(THREADS, 3)
k_gemm(const float* __restrict__ t, const float* __restrict__ s,
       const uint4* __restrict__ kblk, float* __restrict__ ghist){
    __shared__ __align__(1024) int4 smem4[WPB*WAVE_B/16];   // 49152 B
    __shared__ unsigned kred[WPB][4];

    int tid = threadIdx.x;
    int lane = tid & 63;
    int warp = tid >> 6;
    int rrow = lane & 15;                  // fragment row/col within 16-tile
    int kgrp = lane >> 4;                  // C/D row group
    int b = blockIdx.y;

    char* As = (char*)smem4 + warp*WAVE_B; // this wave's tiles
    char* Bs = As + TILE_B;

    // zero tiles (wave-private: no barrier needed). 768 int4 = 12 per lane.
    {
        int4* wz = (int4*)As;
        int4 z4 = {0,0,0,0};
        #pragma unroll
        for (int i = 0; i < 12; ++i)
            wz[i*64 + lane] = z4;
    }

    // reduce the 512 per-block key quads (redundant per block; ~L2-hit)
    {
        unsigned m0=0u, m1=0u, m2=0u, m3=0u;
        #pragma unroll
        for (int i = 0; i < 2; ++i){
            uint4 q = kblk[tid + i*256];
            m0 = max(m0, q.x); m1 = max(m1, q.y);
            m2 = max(m2, q.z); m3 = max(m3, q.w);
        }
        #pragma unroll
        for (int off = 32; off; off >>= 1){
            m0 = max(m0, __shfl_down(m0, off));
            m1 = max(m1, __shfl_down(m1, off));
            m2 = max(m2, __shfl_down(m2, off));
            m3 = max(m3, __shfl_down(m3, off));
        }
        if (lane == 0){
            kred[warp][0] = m0; kred[warp][1] = m1;
            kred[warp][2] = m2; kred[warp][3] = m3;
        }
        __syncthreads();
    }
    unsigned k0=0u,k1=0u,k2=0u,k3=0u;
    #pragma unroll
    for (int j = 0; j < WPB; ++j){
        k0 = max(k0, kred[j][0]); k1 = max(k1, kred[j][1]);
        k2 = max(k2, kred[j][2]); k3 = max(k3, kred[j][3]);
    }
    float tmax =  fdecode(k0), tmin = -fdecode(k1);
    float smax =  fdecode(k2), smin = -fdecode(k3);
    float tsc = 64.f / (tmax - tmin);
    float ssc = 64.f / (smax - smin);

    const float* tb = t + (size_t)b*BATCH_N;
    const float* sb = s + (size_t)b*BATCH_N;

    v4i acc[4][4];
    #pragma unroll
    for (int i = 0; i < 4; ++i)
        #pragma unroll
        for (int j = 0; j < 4; ++j)
            acc[i][j] = (v4i){0,0,0,0};

    int c0 = blockIdx.x*WPB + warp;        // wave slot within batch [0, 1536)
    int vrow = lane << 4;                  // voxel's 16-byte row offset
    unsigned abase = (unsigned)(unsigned long long)As;  // LDS byte offset
    unsigned bbase = (unsigned)(unsigned long long)Bs;

    // depth-2 prefetch pipeline + pack-ahead
    float tq0 = tb[(size_t)c0*64 + lane];
    float sq0 = sb[(size_t)c0*64 + lane];
    float tq1 = tb[(size_t)(c0 + GWAVES)*64 + lane];
    float sq1 = sb[(size_t)(c0 + GWAVES)*64 + lane];

    v4i av0, av1, bv0, bv1; int ga, gb;
    PACK(tq0, tmin, tsc, ga, av0, av1);
    PACK(sq0, smin, ssc, gb, bv0, bv1);

    for (int it = 0; it < NCHUNK; ++it){
        // scatter: voxel-owned 16B rows -> bank-uniform b128 writes
        char* pa = As + ga*BBLK_B + vrow;
        char* pb = Bs + gb*BBLK_B + vrow;
        *(v4i*)pa            = av0;
        *(v4i*)(pa + BBLK_B) = av1;
        *(v4i*)pb            = bv0;
        *(v4i*)(pb + BBLK_B) = bv1;

        __asm__ volatile("" ::: "memory");   // pin scatters before tr reads

        // hardware-transpose fragment reads: block m+1 = bins m*16..m*16+15,
        // slabs at +0/+512 = voxels 0..31 / 32..63 (K-permuted, same for A/B)
        v2i a00,a01,a10,a11,a20,a21,a30,a31;
        v2i b00,b01,b10,b11,b20,b21,b30,b31;
        asm volatile("ds_read_b64_tr_b8 %0, %1 offset:1024" : "=v"(a00) : "v"(abase));
        asm volatile("ds_read_b64_tr_b8 %0, %1 offset:1536" : "=v"(a01) : "v"(abase));
        asm volatile("ds_read_b64_tr_b8 %0, %1 offset:2048" : "=v"(a10) : "v"(abase));
        asm volatile("ds_read_b64_tr_b8 %0, %1 offset:2560" : "=v"(a11) : "v"(abase));
        asm volatile("ds_read_b64_tr_b8 %0, %1 offset:3072" : "=v"(a20) : "v"(abase));
        asm volatile("ds_read_b64_tr_b8 %0, %1 offset:3584" : "=v"(a21) : "v"(abase));
        asm volatile("ds_read_b64_tr_b8 %0, %1 offset:4096" : "=v"(a30) : "v"(abase));
        asm volatile("ds_read_b64_tr_b8 %0, %1 offset:4608" : "=v"(a31) : "v"(abase));
        asm volatile("ds_read_b64_tr_b8 %0, %1 offset:1024" : "=v"(b00) : "v"(bbase));
        asm volatile("ds_read_b64_tr_b8 %0, %1 offset:1536" : "=v"(b01) : "v"(bbase));
        asm volatile("ds_read_b64_tr_b8 %0, %1 offset:2048" : "=v"(b10) : "v"(bbase));
        asm volatile("ds_read_b64_tr_b8 %0, %1 offset:2560" : "=v"(b11) : "v"(bbase));
        asm volatile("ds_read_b64_tr_b8 %0, %1 offset:3072" : "=v"(b20) : "v"(bbase));
        asm volatile("ds_read_b64_tr_b8 %0, %1 offset:3584" : "=v"(b21) : "v"(bbase));
        asm volatile("ds_read_b64_tr_b8 %0, %1 offset:4096" : "=v"(b30) : "v"(bbase));
        asm volatile("ds_read_b64_tr_b8 %0, %1 offset:4608" : "=v"(b31) : "v"(bbase));

        // overlap window: global prefetch (chunk it+2) + pack for chunk it+1.
        // These schedule between read-issue and the fence (can't cross it).
        int cpre = c0 + (it < NCHUNK-2 ? (it + 2)*GWAVES : 0);
        float tnn = tb[(size_t)cpre*64 + lane];
        float snn = sb[(size_t)cpre*64 + lane];
        v4i nav0, nav1, nbv0, nbv1; int nga, ngb;
        PACK(tq1, tmin, tsc, nga, nav0, nav1);
        PACK(sq1, smin, ssc, ngb, nbv0, nbv1);

        asm volatile("s_waitcnt lgkmcnt(0)" ::: "memory");
        __builtin_amdgcn_sched_barrier(0);   // rule #18: stop MFMA hoisting

        v4i af[4], bf[4];
        af[0] = (v4i){a00.x, a00.y, a01.x, a01.y};
        af[1] = (v4i){a10.x, a10.y, a11.x, a11.y};
        af[2] = (v4i){a20.x, a20.y, a21.x, a21.y};
        af[3] = (v4i){a30.x, a30.y, a31.x, a31.y};
        bf[0] = (v4i){b00.x, b00.y, b01.x, b01.y};
        bf[1] = (v4i){b10.x, b10.y, b11.x, b11.y};
        bf[2] = (v4i){b20.x, b20.y, b21.x, b21.y};
        bf[3] = (v4i){b30.x, b30.y, b31.x, b31.y};
        #pragma unroll
        for (int m = 0; m < 4; ++m)
            #pragma unroll
            for (int n = 0; n < 4; ++n)
                acc[m][n] = __builtin_amdgcn_mfma_i32_16x16x64_i8(af[m], bf[n], acc[m][n], 0, 0, 0);

        // zero-restore the two written rows per matrix (in-order after reads)
        __asm__ volatile("" ::: "memory");
        {
            v4i z = (v4i){0,0,0,0};
            *(v4i*)pa = z; *(v4i*)(pa + BBLK_B) = z;
            *(v4i*)pb = z; *(v4i*)(pb + BBLK_B) = z;
        }

        av0 = nav0; av1 = nav1; ga = nga;
        bv0 = nbv0; bv1 = nbv1; gb = ngb;
        tq0 = tq1; sq0 = sq1;
        tq1 = tnn; sq1 = snn;
    }

    // merge: reuse tile LDS (dead now) as f32 staging. Pair p = warp>>1 uses
    // region at smem + p*2*WAVE_B (2 regions x 16896 B). Even warp stores,
    // odd warp adds; then cooperative sum -> global f32 atomics into ghist.
    const float dq = 1.f / (QS*QS);
    float* fmw = (float*)((char*)smem4 + (warp >> 1)*(2*WAVE_B));
    __syncthreads();                       // all waves done with their tiles
    if ((warp & 1) == 0){
        #pragma unroll
        for (int m = 0; m < 4; ++m)
            #pragma unroll
            for (int n = 0; n < 4; ++n)
                #pragma unroll
                for (int r = 0; r < 4; ++r)
                    fmw[(m*16 + kgrp*4 + r)*MROW + n*16 + rrow] = (float)acc[m][n][r] * dq;
    }
    __syncthreads();
    if ((warp & 1) == 1){
        #pragma unroll
        for (int m = 0; m < 4; ++m)
            #pragma unroll
            for (int n = 0; n < 4; ++n)
                #pragma unroll
                for (int r = 0; r < 4; ++r)
                    fmw[(m*16 + kgrp*4 + r)*MROW + n*16 + rrow] += (float)acc[m][n][r] * dq;
    }
    __syncthreads();
    {
        const float* fm0 = (const float*)smem4;
        const float* fm1 = (const float*)((char*)smem4 + 2*WAVE_B);
        float* g = ghist + b*4096;
        #pragma unroll
        for (int i = 0; i < 16; ++i){
            int idx = i*256 + tid;
            int l = (idx >> 6)*MROW + (idx & 63);
            unsafeAtomicAdd(&g[idx], fm0[l] + fm1[l]);
        }
    }
}

__device__ __forceinline__ float blockReduceSum(float v, float* red){
    #pragma unroll
    for (int off = 32; off; off >>= 1) v += __shfl_down(v, off);
    int wid = threadIdx.x >> 6, lane = threadIdx.x & 63;
    __syncthreads();              // protect red[] from previous round
    if (lane == 0) red[wid] = v;
    __syncthreads();
    return red[0] + red[1] + red[2] + red[3];
}

__global__ void k_final(const float* __restrict__ hist, float* __restrict__ out){
    __shared__ float sh[2*4096];
    __shared__ float red[4];
    int tid = threadIdx.x;
    for (int i = tid; i < 8192; i += 256) sh[i] = hist[i];
    __syncthreads();

    float loc = 0.f;
    for (int i = tid; i < 8192; i += 256) loc += sh[i];
    float total = blockReduceSum(loc, red);
    float inv = 1.f / total;

    float nmi[2];
    for (int b = 0; b < 2; ++b){
        const float* h = sh + b*4096;
        float lj = 0.f;
        for (int i = tid; i < 4096; i += 256){
            float p = h[i]*inv;
            lj += p*logf(p + 1e-12f);
        }
        float Hj = -blockReduceSum(lj, red);
        float lt = 0.f;
        if (tid < 64){
            float r = 0.f;
            for (int j = 0; j < 64; ++j) r += h[tid*64 + j];
            float p = r*inv;
            lt = p*logf(p + 1e-12f);
        }
        float Ht = -blockReduceSum(lt, red);
        float ls = 0.f;
        if (tid < 64){
            float c = 0.f;
            for (int j = 0; j < 64; ++j) c += h[j*64 + tid];
            float p = c*inv;
            ls = p*logf(p + 1e-12f);
        }
        float Hs = -blockReduceSum(ls, red);
        nmi[b] = (Ht + Hs) / Hj;
    }
    if (tid == 0) out[0] = -0.5f*(nmi[0] + nmi[1]);
}

extern "C" void kernel_launch(void* const* d_in, const int* in_sizes, int n_in,
                              void* d_out, int out_size, void* d_ws, size_t ws_size,
                              hipStream_t stream) {
    const float* t = (const float*)d_in[0];
    const float* s = (const float*)d_in[1];
    float* out = (float*)d_out;
    float* ghist = (float*)((char*)d_ws + OFF_GHIST);
    uint4* kblk  = (uint4*)((char*)d_ws + OFF_KBLK);

    // no memset node: kblk plain-stored + ghist zeroed by k_minmax; k_gemm
    // atomically accumulates ghist. Kernel boundaries provide visibility.
    k_minmax<<<KBLK, 256, 0, stream>>>((const float4*)t, (const float4*)s, NTOT/4, kblk, ghist);
    k_gemm<<<dim3(GBX, 2), THREADS, 0, stream>>>(t, s, kblk, ghist);
    k_final<<<1, 256, 0, stream>>>(ghist, out);
}

// Round 8
// 97.218 us; speedup vs baseline: 1.0876x; 1.0876x over previous
//
#include <hip/hip_runtime.h>
#include <math.h>

#define BATCH_N 884736    // 96*96*96
#define NTOT   1769472    // 2*BATCH_N
#define ROWB  80          // tile row stride bytes (64 voxels + 16 pad, 16B aligned)
#define TILE_B 5440       // 68*80 bytes per tile (rows -1..66 padded)
#define WAVE_B 10880      // A+B tiles per wave
#define MROW 66           // merge region row stride (floats)
#define QS 190.0f         // weight quantization scale (max w=2/3 -> 127)
#define GBLK 216          // k_gemm blocks per batch (4 waves each)
#define GWAVES 864        // waves per batch: 13824/864 = exactly 16 chunks/wave
#define KBLK 512          // k_minmax blocks

// ws layout (bytes):
//   ghist  at   256 : float[2][4096]   (zeroed by k_minmax; atomic-accumulated by k_gemm)
//   kblk   at 36864 : uint4[512]       (plain-stored by k_minmax)
#define OFF_GHIST 256
#define OFF_KBLK 36864

typedef int  v4i __attribute__((ext_vector_type(4)));

// monotone float->uint key: max over keys == max over floats
__device__ __forceinline__ unsigned fkey(float x){
    unsigned u = __float_as_uint(x);
    return (u & 0x80000000u) ? ~u : (u | 0x80000000u);
}
__device__ __forceinline__ float fdecode(unsigned k){
    return __uint_as_float((k & 0x80000000u) ? (k ^ 0x80000000u) : ~k);
}

// cubic B-spline weights for the 4 bins it0-1..it0+2, u = frac(vt) in [0,1)
__device__ __forceinline__ void bw4(float u, float w[4]){
    float um = 1.f - u;
    float u2 = u*u, um2 = um*um;
    w[0] = um2*um*(1.f/6.f);
    w[3] = u2*u*(1.f/6.f);
    w[1] = 0.6666666666666667f - u2 + 0.5f*u2*u;
    w[2] = 0.6666666666666667f - um2 + 0.5f*um2*um;
}

// per-block min/max -> plain store into kblk[block]; blocks 0..7 also zero ghist
__global__ void __launch_bounds__(256)
k_minmax(const float4* __restrict__ t4, const float4* __restrict__ s4,
         int n4, uint4* __restrict__ kblk, float* __restrict__ ghist){
    __shared__ unsigned red[4][4];   // [wave][key]

    if (blockIdx.x < 8){
        ghist[blockIdx.x*1024 + threadIdx.x] = 0.f;
        ghist[blockIdx.x*1024 + 256 + threadIdx.x] = 0.f;
        ghist[blockIdx.x*1024 + 512 + threadIdx.x] = 0.f;
        ghist[blockIdx.x*1024 + 768 + threadIdx.x] = 0.f;
    }

    unsigned mt=0u, mnt=0u, ms=0u, mns=0u;
    int stride = gridDim.x * blockDim.x;
    for (int i = blockIdx.x*blockDim.x + threadIdx.x; i < n4; i += stride){
        float4 a = t4[i];
        float4 b = s4[i];
        mt  = max(mt,  max(max(fkey(a.x),  fkey(a.y)),  max(fkey(a.z),  fkey(a.w))));
        mnt = max(mnt, max(max(fkey(-a.x), fkey(-a.y)), max(fkey(-a.z), fkey(-a.w))));
        ms  = max(ms,  max(max(fkey(b.x),  fkey(b.y)),  max(fkey(b.z),  fkey(b.w))));
        mns = max(mns, max(max(fkey(-b.x), fkey(-b.y)), max(fkey(-b.z), fkey(-b.w))));
    }
    #pragma unroll
    for (int off = 32; off; off >>= 1){
        mt  = max(mt,  __shfl_down(mt,  off));
        mnt = max(mnt, __shfl_down(mnt, off));
        ms  = max(ms,  __shfl_down(ms,  off));
        mns = max(mns, __shfl_down(mns, off));
    }
    int wid = threadIdx.x >> 6;
    if ((threadIdx.x & 63) == 0){
        red[wid][0] = mt; red[wid][1] = mnt; red[wid][2] = ms; red[wid][3] = mns;
    }
    __syncthreads();
    if (threadIdx.x == 0){
        uint4 q;
        q.x = max(max(red[0][0], red[1][0]), max(red[2][0], red[3][0]));
        q.y = max(max(red[0][1], red[1][1]), max(red[2][1], red[3][1]));
        q.z = max(max(red[0][2], red[1][2]), max(red[2][2], red[3][2]));
        q.w = max(max(red[0][3], red[1][3]), max(red[2][3], red[3][3]));
        kblk[blockIdx.x] = q;
    }
}

// joint histogram as tall-skinny GEMM on int8 (wave-private LDS tiles, i8 MFMA).
// 4 waves/block, exactly 16 chunks/wave; depth-2 global prefetch.
// Epilogue: pairwise LDS merge (waves 0,1 -> fm0 ; waves 2,3 -> fm1) then
// global f32 atomic add into ghist (no partials, no reduce kernel).
__global__ void __launch_bounds__(256)
k_gemm(const float* __restrict__ t, const float* __restrict__ s,
       const uint4* __restrict__ kblk, float* __restrict__ ghist){
    __shared__ int4 smem4[2720];           // 43520 B = 4 waves * (A+B i8 tiles)
    __shared__ unsigned kred[4][4];

    int tid = threadIdx.x;
    int lane = tid & 63;
    int warp = tid >> 6;
    int rrow = lane & 15;                  // fragment row/col within 16-tile
    int kgrp = lane >> 4;                  // k-group (16 bytes each for K=64 i8)
    int b = blockIdx.y;

    char* As = (char*)smem4 + warp*WAVE_B; // this wave's tiles
    char* Bs = As + TILE_B;

    // initial clear of this wave's tiles (wave-private: no barrier needed)
    {
        int4* wz = (int4*)As;
        int4 z4 = {0,0,0,0};
        #pragma unroll
        for (int i = 0; i < 11; ++i){
            int idx = i*64 + lane;
            if (idx < WAVE_B/16) wz[idx] = z4;
        }
    }

    // reduce the 512 per-block key quads (redundant per block; ~L2-hit)
    {
        unsigned m0=0u, m1=0u, m2=0u, m3=0u;
        #pragma unroll
        for (int i = 0; i < 2; ++i){
            uint4 q = kblk[tid + i*256];
            m0 = max(m0, q.x); m1 = max(m1, q.y);
            m2 = max(m2, q.z); m3 = max(m3, q.w);
        }
        #pragma unroll
        for (int off = 32; off; off >>= 1){
            m0 = max(m0, __shfl_down(m0, off));
            m1 = max(m1, __shfl_down(m1, off));
            m2 = max(m2, __shfl_down(m2, off));
            m3 = max(m3, __shfl_down(m3, off));
        }
        if (lane == 0){
            kred[warp][0] = m0; kred[warp][1] = m1;
            kred[warp][2] = m2; kred[warp][3] = m3;
        }
        __syncthreads();
    }
    float tmax =  fdecode(max(max(kred[0][0], kred[1][0]), max(kred[2][0], kred[3][0])));
    float tmin = -fdecode(max(max(kred[0][1], kred[1][1]), max(kred[2][1], kred[3][1])));
    float smax =  fdecode(max(max(kred[0][2], kred[1][2]), max(kred[2][2], kred[3][2])));
    float smin = -fdecode(max(max(kred[0][3], kred[1][3]), max(kred[2][3], kred[3][3])));
    float tsc = 64.f / (tmax - tmin);
    float ssc = 64.f / (smax - smin);

    const float* tb = t + (size_t)b*BATCH_N;
    const float* sb = s + (size_t)b*BATCH_N;

    v4i acc[4][4];
    #pragma unroll
    for (int i = 0; i < 4; ++i)
        #pragma unroll
        for (int j = 0; j < 4; ++j)
            acc[i][j] = (v4i){0,0,0,0};

    int c0 = blockIdx.x*4 + warp;          // wave index within batch [0, 864)
    // depth-2 prefetch pipeline
    float tq0 = tb[(size_t)c0*64 + lane];
    float sq0 = sb[(size_t)c0*64 + lane];
    float tq1 = tb[(size_t)(c0 + GWAVES)*64 + lane];
    float sq1 = sb[(size_t)(c0 + GWAVES)*64 + lane];

    #pragma unroll 2
    for (int it = 0; it < 16; ++it){
        // issue prefetch for chunk it+2 (clamped to a safe in-range address)
        int cpre = c0 + (it < 14 ? (it + 2)*GWAVES : 0);
        float tnn = tb[(size_t)cpre*64 + lane];
        float snn = sb[(size_t)cpre*64 + lane];

        float vt = (tq0 - tmin) * tsc;     // in [0,64]
        float vs = (sq0 - smin) * ssc;
        int it0 = (int)floorf(vt);         // 0..64
        int is0 = (int)floorf(vs);
        float wt[4], wsv[4];
        bw4(vt - (float)it0, wt);
        bw4(vs - (float)is0, wsv);

        // quantized scatter: lane owns voxel column `lane`; padded rows it0..it0+3
        // (bin it0-1..it0+2 shifted +1), unconditional — pad rows are never read.
        char* pa = As + it0*ROWB + lane;
        char* pb = Bs + is0*ROWB + lane;
        #pragma unroll
        for (int k = 0; k < 4; ++k){
            pa[k*ROWB] = (char)__float2int_rn(wt[k]  * QS);
            pb[k*ROWB] = (char)__float2int_rn(wsv[k] * QS);
        }

        // fragments + MFMA (same-wave DS ops complete in order)
        v4i af[4], bf[4];
        #pragma unroll
        for (int m = 0; m < 4; ++m)
            af[m] = *(const v4i*)(As + (m*16 + rrow + 1)*ROWB + kgrp*16);
        #pragma unroll
        for (int n = 0; n < 4; ++n)
            bf[n] = *(const v4i*)(Bs + (n*16 + rrow + 1)*ROWB + kgrp*16);
        #pragma unroll
        for (int m = 0; m < 4; ++m)
            #pragma unroll
            for (int n = 0; n < 4; ++n)
                acc[m][n] = __builtin_amdgcn_mfma_i32_16x16x64_i8(af[m], bf[n], acc[m][n], 0, 0, 0);

        // zero-restore the scattered entries
        __asm__ volatile("" ::: "memory");
        #pragma unroll
        for (int k = 0; k < 4; ++k){
            pa[k*ROWB] = 0;
            pb[k*ROWB] = 0;
        }

        tq0 = tq1; sq0 = sq1;
        tq1 = tnn; sq1 = snn;
    }

    // merge: reuse tile LDS (dead now) as f32 staging.
    // pair p = warp>>1 uses region fm_p at smem + p*2*WAVE_B (16896 B each).
    // Even warp of the pair stores, odd warp adds; then cooperative global atomics.
    const float dq = 1.f / (QS*QS);
    float* fmw = (float*)((char*)smem4 + (warp >> 1)*(2*WAVE_B));
    __syncthreads();                       // all waves done reading their tiles
    if ((warp & 1) == 0){
        #pragma unroll
        for (int m = 0; m < 4; ++m)
            #pragma unroll
            for (int n = 0; n < 4; ++n)
                #pragma unroll
                for (int r = 0; r < 4; ++r)
                    fmw[(m*16 + kgrp*4 + r)*MROW + n*16 + rrow] = (float)acc[m][n][r] * dq;
    }
    __syncthreads();
    if ((warp & 1) == 1){
        #pragma unroll
        for (int m = 0; m < 4; ++m)
            #pragma unroll
            for (int n = 0; n < 4; ++n)
                #pragma unroll
                for (int r = 0; r < 4; ++r)
                    fmw[(m*16 + kgrp*4 + r)*MROW + n*16 + rrow] += (float)acc[m][n][r] * dq;
    }
    __syncthreads();
    // cooperative: sum the two pair-regions, atomic-add into ghist
    {
        const float* fm0 = (const float*)smem4;
        const float* fm1 = (const float*)((char*)smem4 + 2*WAVE_B);
        float* g = ghist + b*4096;
        #pragma unroll
        for (int i = 0; i < 16; ++i){
            int idx = i*256 + tid;
            int l = (idx >> 6)*MROW + (idx & 63);
            unsafeAtomicAdd(&g[idx], fm0[l] + fm1[l]);
        }
    }
}

__device__ __forceinline__ float blockReduceSum(float v, float* red){
    #pragma unroll
    for (int off = 32; off; off >>= 1) v += __shfl_down(v, off);
    int wid = threadIdx.x >> 6, lane = threadIdx.x & 63;
    __syncthreads();              // protect red[] from previous round
    if (lane == 0) red[wid] = v;
    __syncthreads();
    return red[0] + red[1] + red[2] + red[3];
}

__global__ void k_final(const float* __restrict__ hist, float* __restrict__ out){
    __shared__ float sh[2*4096];
    __shared__ float red[4];
    int tid = threadIdx.x;
    for (int i = tid; i < 8192; i += 256) sh[i] = hist[i];
    __syncthreads();

    float loc = 0.f;
    for (int i = tid; i < 8192; i += 256) loc += sh[i];
    float total = blockReduceSum(loc, red);
    float inv = 1.f / total;

    float nmi[2];
    for (int b = 0; b < 2; ++b){
        const float* h = sh + b*4096;
        float lj = 0.f;
        for (int i = tid; i < 4096; i += 256){
            float p = h[i]*inv;
            lj += p*logf(p + 1e-12f);
        }
        float Hj = -blockReduceSum(lj, red);
        float lt = 0.f;
        if (tid < 64){
            float r = 0.f;
            for (int j = 0; j < 64; ++j) r += h[tid*64 + j];
            float p = r*inv;
            lt = p*logf(p + 1e-12f);
        }
        float Ht = -blockReduceSum(lt, red);
        float ls = 0.f;
        if (tid < 64){
            float c = 0.f;
            for (int j = 0; j < 64; ++j) c += h[j*64 + tid];
            float p = c*inv;
            ls = p*logf(p + 1e-12f);
        }
        float Hs = -blockReduceSum(ls, red);
        nmi[b] = (Ht + Hs) / Hj;
    }
    if (tid == 0) out[0] = -0.5f*(nmi[0] + nmi[1]);
}

extern "C" void kernel_launch(void* const* d_in, const int* in_sizes, int n_in,
                              void* d_out, int out_size, void* d_ws, size_t ws_size,
                              hipStream_t stream) {
    const float* t = (const float*)d_in[0];
    const float* s = (const float*)d_in[1];
    float* out = (float*)d_out;
    float* ghist = (float*)((char*)d_ws + OFF_GHIST);
    uint4* kblk  = (uint4*)((char*)d_ws + OFF_KBLK);

    // no memset node: kblk plain-stored + ghist zeroed by k_minmax; k_gemm
    // atomically accumulates ghist. Kernel boundaries provide visibility.
    k_minmax<<<KBLK, 256, 0, stream>>>((const float4*)t, (const float4*)s, NTOT/4, kblk, ghist);
    k_gemm<<<dim3(GBLK, 2), 256, 0, stream>>>(t, s, kblk, ghist);
    k_final<<<1, 256, 0, stream>>>(ghist, out);
}